// Round 11
// baseline (400.435 us; speedup 1.0000x reference)
//
#include <hip/hip_runtime.h>
#include <math.h>

#define N_USER 50000
#define N_ITEM 50000
#define NTOT   100000
#define D      128
#define BATCH_ 4096
#define NEG_SLOPE 0.2f
#define EPS_ 1e-12f
#define SCAN_CHUNK 1024
#define NBUK 782            // buckets of 128 rows
#define NCHK 512            // edge chunks for partition (runs ~8 edges = 64B)
#define NSCAN (NBUK * NCHK) // 400384
#define BUKCAP 5120         // max edges/bucket for LDS sort (mean 4092, max ~4400)

typedef __attribute__((ext_vector_type(8))) short bfrag;
typedef __attribute__((ext_vector_type(4))) float f32x4;

static __device__ __forceinline__ float bf2f(unsigned short h) {
    return __uint_as_float(((unsigned)h) << 16);
}
static __device__ __forceinline__ unsigned short f2bf(float f) {
    unsigned u = __float_as_uint(f);
    u += 0x7fffu + ((u >> 16) & 1u);   // round-to-nearest-even
    return (unsigned short)(u >> 16);
}

// ---------------------------------------------------------------- ego0 assembly + W pack (merged)
__global__ void assemble_and_pack(const float* __restrict__ user_emb,
                                  const float* __restrict__ item_emb1,
                                  const float* __restrict__ item_emb2,
                                  const float* __restrict__ feature,
                                  const float* __restrict__ W_gc,
                                  const float* __restrict__ W_bi,
                                  unsigned short* __restrict__ ego0h,
                                  unsigned short* __restrict__ Wp) {
    if (blockIdx.x < 32) {
        int t = blockIdx.x * 256 + threadIdx.x;
        int lane  = t & 63;
        int nt    = (t >> 6) & 7;
        int kt    = (t >> 9) & 3;
        int mat   = (t >> 11) & 1;
        int layer = (t >> 12) & 1;
        const float* W = (mat ? W_bi : W_gc) + (size_t)layer * D * D;
        int n = nt * 16 + (lane & 15);
        int kbase = kt * 32 + (lane >> 4) * 8;
        unsigned short o8[8];
        #pragma unroll
        for (int e = 0; e < 8; ++e) o8[e] = f2bf(W[(size_t)(kbase + e) * D + n]);
        *(int4*)(Wp + (size_t)t * 8) = *(int4*)o8;
        return;
    }
    int t = (blockIdx.x - 32) * 256 + threadIdx.x;   // float4 slot
    const int total = NTOT * (D / 4);
    if (t >= total) return;
    int row = t >> 5;
    int q   = t & 31;
    int d0  = q * 4;
    const float* src;
    if (d0 < 64) {
        src = (row < N_USER) ? user_emb  + (size_t)row * 64 + d0
                             : item_emb1 + (size_t)(row - N_USER) * 64 + d0;
    } else {
        src = (row < N_USER) ? feature   + (size_t)row * 64 + (d0 - 64)
                             : item_emb2 + (size_t)(row - N_USER) * 64 + (d0 - 64);
    }
    float4 v = *(const float4*)src;
    ushort4 h;
    h.x = f2bf(v.x); h.y = f2bf(v.y); h.z = f2bf(v.z); h.w = f2bf(v.w);
    *(ushort4*)(ego0h + (size_t)row * D + d0) = h;
}

// ---------------------------------------------------------------- bucket histogram (chunk-blocks, 512 thr)
__global__ __launch_bounds__(512) void hist_buckets(const int* __restrict__ rows,
                                                    int* __restrict__ cnt2,
                                                    int nnz, int chunk_sz) {
    __shared__ int h[NBUK];
    for (int i = threadIdx.x; i < NBUK; i += 512) h[i] = 0;
    __syncthreads();
    int c = blockIdx.x;
    int base = c * chunk_sz, end = min(base + chunk_sz, nnz);
    for (int e = base + threadIdx.x; e < end; e += 512)
        atomicAdd(&h[rows[e] >> 7], 1);
    __syncthreads();
    for (int b = threadIdx.x; b < NBUK; b += 512)
        cnt2[b * NCHK + c] = h[b];      // bucket-major: scan gives bucket-contiguous ranges
}

// ---------------------------------------------------------------- scan (3-pass, n = NSCAN)
__global__ __launch_bounds__(1024) void scan_block_sums(const int* __restrict__ cnt,
                                                        int* __restrict__ bsum, int n) {
    __shared__ int ws[16];
    int i = blockIdx.x * SCAN_CHUNK + threadIdx.x;
    int x = (i < n) ? cnt[i] : 0;
    #pragma unroll
    for (int d = 32; d >= 1; d >>= 1) x += __shfl_xor(x, d);
    int wid = threadIdx.x >> 6, lane = threadIdx.x & 63;
    if (lane == 0) ws[wid] = x;
    __syncthreads();
    if (threadIdx.x == 0) {
        int s = 0;
        #pragma unroll
        for (int k = 0; k < 16; ++k) s += ws[k];
        bsum[blockIdx.x] = s;
    }
}

__global__ void scan_small(const int* __restrict__ bsum, int* __restrict__ boff, int nb) {
    if (threadIdx.x == 0 && blockIdx.x == 0) {
        int acc = 0;
        for (int i = 0; i < nb; ++i) { boff[i] = acc; acc += bsum[i]; }
    }
}

__global__ __launch_bounds__(1024) void scan_chunks(const int* __restrict__ cnt,
                                                    const int* __restrict__ boff,
                                                    int* __restrict__ off, int n) {
    __shared__ int ws[16];
    int tid = threadIdx.x;
    int i = blockIdx.x * SCAN_CHUNK + tid;
    int x = (i < n) ? cnt[i] : 0;
    int v = x;
    #pragma unroll
    for (int d = 1; d < 64; d <<= 1) { int u = __shfl_up(v, d); if ((tid & 63) >= d) v += u; }
    int wid = tid >> 6, lane = tid & 63;
    if (lane == 63) ws[wid] = v;
    __syncthreads();
    if (wid == 0) {
        int s = (lane < 16) ? ws[lane] : 0;
        #pragma unroll
        for (int d = 1; d < 16; d <<= 1) { int u = __shfl_up(s, d); if (lane >= d) s += u; }
        if (lane < 16) ws[lane] = s;
    }
    __syncthreads();
    int woff = (wid == 0) ? 0 : ws[wid - 1];
    if (i < n) off[i] = boff[blockIdx.x] + woff + v - x;
}

// ---------------------------------------------------------------- partition into buckets (no global atomics, 512 thr)
__global__ __launch_bounds__(512) void partition_edges(
        const int* __restrict__ rows, const int* __restrict__ cols,
        const float* __restrict__ vals, const float* __restrict__ w3,
        const int* __restrict__ scanout, int2* __restrict__ tmp8,
        int nnz, int chunk_sz) {
    __shared__ int cur[NBUK];
    int c = blockIdx.x;
    for (int b = threadIdx.x; b < NBUK; b += 512) cur[b] = scanout[b * NCHK + c];
    __syncthreads();
    const float w0 = w3[0], w1 = w3[1], w2 = w3[2];
    int base = c * chunk_sz, end = min(base + chunk_sz, nnz);
    for (int e = base + threadIdx.x; e < end; e += 512) {
        int r = rows[e];
        float v = vals[e];
        float v2 = v * v;
        float comb = w0 * v + w1 * v2 + w2 * v2 * v2 * v2;
        int pos = atomicAdd(&cur[r >> 7], 1);
        tmp8[pos] = make_int2(((r & 127) << 17) | cols[e], __float_as_int(comb));
    }
}

// ---------------------------------------------------------------- in-bucket LDS counting sort -> 4B edges + row_off
__global__ __launch_bounds__(256) void bucket_sort(
        const int2* __restrict__ tmp8, const int* __restrict__ scanout,
        unsigned* __restrict__ edges4, int* __restrict__ row_off, int nnz) {
    __shared__ int hist[128], exc[129], cur[128];
    __shared__ unsigned st[BUKCAP];
    int b = blockIdx.x;
    int lo = scanout[b * NCHK];
    int hi = (b + 1 < NBUK) ? scanout[(b + 1) * NCHK] : nnz;
    int cnt = hi - lo;
    if (threadIdx.x < 128) hist[threadIdx.x] = 0;
    __syncthreads();
    for (int i = lo + threadIdx.x; i < hi; i += 256)
        atomicAdd(&hist[tmp8[i].x >> 17], 1);
    __syncthreads();
    if (threadIdx.x == 0) {
        int a = 0;
        for (int r = 0; r < 128; ++r) { exc[r] = a; a += hist[r]; }
        exc[128] = a;
    }
    __syncthreads();
    if (threadIdx.x < 128) {
        cur[threadIdx.x] = exc[threadIdx.x];
        int grow = b * 128 + threadIdx.x;
        if (grow <= NTOT) row_off[grow] = lo + exc[threadIdx.x];
    }
    __syncthreads();
    if (cnt <= BUKCAP) {
        for (int i = lo + threadIdx.x; i < hi; i += 256) {
            int2 t = tmp8[i];
            int rl = t.x >> 17;
            int p = atomicAdd(&cur[rl], 1);
            unsigned cb = (unsigned)f2bf(__int_as_float(t.y)) & 0x7FFFu;  // comb>0 -> sign 0
            st[p] = (cb << 17) | ((unsigned)t.x & 0x1FFFFu);
        }
        __syncthreads();
        for (int i = threadIdx.x; i < cnt; i += 256)
            edges4[lo + i] = st[i];                   // fully coalesced
    } else {
        // statistically unreachable fallback (cnt > BUKCAP)
        for (int i = lo + threadIdx.x; i < hi; i += 256) {
            int2 t = tmp8[i];
            int rl = t.x >> 17;
            int p = atomicAdd(&cur[rl], 1);
            unsigned cb = (unsigned)f2bf(__int_as_float(t.y)) & 0x7FFFu;
            edges4[lo + p] = (cb << 17) | ((unsigned)t.x & 0x1FFFFu);
        }
    }
}

// ---------------------------------------------------------------- SpMM (CSR, wave/row, 4-edge groups, 4-deep unroll)
__global__ __launch_bounds__(256) void spmm_csr_h(const int* __restrict__ row_off,
                                                  const unsigned* __restrict__ edges4,
                                                  const unsigned short* __restrict__ Xh,
                                                  unsigned short* __restrict__ side_h) {
    int row = (blockIdx.x * blockDim.x + threadIdx.x) >> 6;
    if (row >= NTOT) return;
    int lane = threadIdx.x & 63;
    int g = lane >> 4;        // edge slot 0..3
    int q = lane & 15;        // dim slice: dims q*8 .. q*8+7
    int s = row_off[row], e = row_off[row + 1];

    float a[8];
    #pragma unroll
    for (int j = 0; j < 8; ++j) a[j] = 0.f;

    for (int i = s; i < e; i += 16) {
        int i0 = i + g, i1 = i + 4 + g, i2 = i + 8 + g, i3 = i + 12 + g;
        unsigned e0 = (i0 < e) ? edges4[i0] : 0u;
        unsigned e1 = (i1 < e) ? edges4[i1] : 0u;
        unsigned e2 = (i2 < e) ? edges4[i2] : 0u;
        unsigned e3 = (i3 < e) ? edges4[i3] : 0u;
        float v0 = bf2f((unsigned short)(e0 >> 17));
        float v1 = bf2f((unsigned short)(e1 >> 17));
        float v2 = bf2f((unsigned short)(e2 >> 17));
        float v3 = bf2f((unsigned short)(e3 >> 17));
        int4 x0 = *(const int4*)(Xh + (size_t)(e0 & 0x1FFFFu) * D + q * 8);
        int4 x1 = *(const int4*)(Xh + (size_t)(e1 & 0x1FFFFu) * D + q * 8);
        int4 x2 = *(const int4*)(Xh + (size_t)(e2 & 0x1FFFFu) * D + q * 8);
        int4 x3 = *(const int4*)(Xh + (size_t)(e3 & 0x1FFFFu) * D + q * 8);
        const unsigned short* p0 = (const unsigned short*)&x0;
        const unsigned short* p1 = (const unsigned short*)&x1;
        const unsigned short* p2 = (const unsigned short*)&x2;
        const unsigned short* p3 = (const unsigned short*)&x3;
        #pragma unroll
        for (int j = 0; j < 8; ++j)
            a[j] += v0 * bf2f(p0[j]) + v1 * bf2f(p1[j])
                  + v2 * bf2f(p2[j]) + v3 * bf2f(p3[j]);
    }
    #pragma unroll
    for (int j = 0; j < 8; ++j) {
        a[j] += __shfl_xor(a[j], 16);
        a[j] += __shfl_xor(a[j], 32);
    }
    if (g == 0) {
        unsigned short o[8];
        #pragma unroll
        for (int j = 0; j < 8; ++j) o[j] = f2bf(a[j]);
        *(int4*)(side_h + (size_t)row * D + q * 8) = *(int4*)o;
    }
}

// ---------------------------------------------------------------- fused MFMA layer GEMM
__global__ __launch_bounds__(256) void layer_gemm_mfma(
        const unsigned short* __restrict__ side_h,
        const unsigned short* __restrict__ ego_h,
        const unsigned short* __restrict__ Wp, int layer,
        const float* __restrict__ bgc, const float* __restrict__ bbi,
        unsigned short* __restrict__ ego_out_h, float* __restrict__ norms) {
    __shared__ unsigned short Sl[64 * D];
    __shared__ unsigned short Pl[64 * D];
    __shared__ float sqp[4][64];

    const int r0  = blockIdx.x * 64;
    const int tid = threadIdx.x;
    const int lane = tid & 63;
    const int wv   = tid >> 6;

    #pragma unroll
    for (int it = 0; it < 4; ++it) {
        int c = tid + it * 256;
        int r = c >> 4;
        int q = c & 15;
        int row = r0 + r;
        int4 sv = make_int4(0, 0, 0, 0), ev = make_int4(0, 0, 0, 0);
        if (row < NTOT) {
            sv = *(const int4*)(side_h + (size_t)row * D + q * 8);
            ev = *(const int4*)(ego_h  + (size_t)row * D + q * 8);
        }
        int dst = (r * 256 + q * 16) ^ ((r & 7) << 4);
        *(int4*)((char*)Sl + dst) = sv;
        const unsigned short* sp = (const unsigned short*)&sv;
        const unsigned short* ep = (const unsigned short*)&ev;
        unsigned short pv[8];
        #pragma unroll
        for (int j = 0; j < 8; ++j) pv[j] = f2bf(bf2f(sp[j]) * bf2f(ep[j]));
        *(int4*)((char*)Pl + dst) = *(int4*)pv;
    }

    bfrag wg[4][2], wb[4][2];
    #pragma unroll
    for (int kt = 0; kt < 4; ++kt)
        #pragma unroll
        for (int n2 = 0; n2 < 2; ++n2) {
            int nt = wv * 2 + n2;
            size_t og = ((((size_t)(layer * 2 + 0) * 4 + kt) * 8 + nt) * 64 + lane) * 8;
            size_t ob = ((((size_t)(layer * 2 + 1) * 4 + kt) * 8 + nt) * 64 + lane) * 8;
            wg[kt][n2] = *(const bfrag*)(Wp + og);
            wb[kt][n2] = *(const bfrag*)(Wp + ob);
        }

    __syncthreads();

    f32x4 acc[4][2];
    #pragma unroll
    for (int m = 0; m < 4; ++m)
        #pragma unroll
        for (int n = 0; n < 2; ++n) acc[m][n] = (f32x4){0.f, 0.f, 0.f, 0.f};

    #pragma unroll
    for (int kt = 0; kt < 4; ++kt) {
        bfrag sf[4], pf[4];
        #pragma unroll
        for (int m = 0; m < 4; ++m) {
            int rowl = m * 16 + (lane & 15);
            int byte = (rowl * 256 + kt * 64 + (lane >> 4) * 16) ^ ((rowl & 7) << 4);
            sf[m] = *(const bfrag*)((const char*)Sl + byte);
            pf[m] = *(const bfrag*)((const char*)Pl + byte);
        }
        #pragma unroll
        for (int m = 0; m < 4; ++m)
            #pragma unroll
            for (int n = 0; n < 2; ++n) {
                acc[m][n] = __builtin_amdgcn_mfma_f32_16x16x32_bf16(sf[m], wg[kt][n], acc[m][n], 0, 0, 0);
                acc[m][n] = __builtin_amdgcn_mfma_f32_16x16x32_bf16(pf[m], wb[kt][n], acc[m][n], 0, 0, 0);
            }
    }

    float bsum[2];
    #pragma unroll
    for (int n = 0; n < 2; ++n) {
        int col = wv * 32 + n * 16 + (lane & 15);
        bsum[n] = bgc[col] + bbi[col];
    }

    float sq[4][4];
    #pragma unroll
    for (int m = 0; m < 4; ++m)
        #pragma unroll
        for (int r = 0; r < 4; ++r) sq[m][r] = 0.f;

    #pragma unroll
    for (int m = 0; m < 4; ++m) {
        int rowl = m * 16 + (lane >> 4) * 4;
        #pragma unroll
        for (int n = 0; n < 2; ++n) {
            int col = wv * 32 + n * 16 + (lane & 15);
            #pragma unroll
            for (int r = 0; r < 4; ++r) {
                float o = acc[m][n][r] + bsum[n];
                o = (o > 0.f) ? o : NEG_SLOPE * o;
                sq[m][r] += o * o;
                int row = r0 + rowl + r;
                if (row < NTOT)
                    ego_out_h[(size_t)row * D + col] = f2bf(o);
            }
        }
    }

    #pragma unroll
    for (int m = 0; m < 4; ++m)
        #pragma unroll
        for (int r = 0; r < 4; ++r) {
            float v = sq[m][r];
            #pragma unroll
            for (int off = 8; off >= 1; off >>= 1) v += __shfl_xor(v, off);
            if ((lane & 15) == 0) sqp[wv][m * 16 + (lane >> 4) * 4 + r] = v;
        }
    __syncthreads();
    if (tid < 64) {
        int row = r0 + tid;
        if (row < NTOT) {
            float s = sqp[0][tid] + sqp[1][tid] + sqp[2][tid] + sqp[3][tid];
            norms[row] = fmaxf(sqrtf(s), EPS_);
        }
    }
}

// ---------------------------------------------------------------- final gather (layer0 from raw f32 inputs)
__global__ void gather_out(const int* __restrict__ users,
                           const int* __restrict__ pos,
                           const int* __restrict__ neg,
                           const float* __restrict__ user_emb,
                           const float* __restrict__ item_emb1,
                           const float* __restrict__ item_emb2,
                           const float* __restrict__ feature,
                           const unsigned short* __restrict__ ego1h,
                           const unsigned short* __restrict__ ego2h,
                           const float* __restrict__ n1,
                           const float* __restrict__ n2,
                           float* __restrict__ out) {
    int t = blockIdx.x * blockDim.x + threadIdx.x;
    const int total = 3 * BATCH_ * 384;
    if (t >= total) return;
    int c = t % 384;
    int i = (t / 384) % BATCH_;
    int s = t / (384 * BATCH_);
    int idx  = (s == 0) ? users[i] : (s == 1 ? pos[i] : neg[i]);
    int node = (s == 0) ? idx : idx + N_USER;
    float val;
    if (c < 128) {
        if (s == 0)
            val = (c < 64) ? user_emb[(size_t)idx * 64 + c]
                           : feature[(size_t)idx * 64 + (c - 64)];
        else
            val = (c < 64) ? item_emb1[(size_t)idx * 64 + c]
                           : item_emb2[(size_t)idx * 64 + (c - 64)];
    } else if (c < 256) {
        val = bf2f(ego1h[(size_t)node * D + (c - 128)]) / n1[node];
    } else {
        val = bf2f(ego2h[(size_t)node * D + (c - 256)]) / n2[node];
    }
    out[t] = val;
}

// ---------------------------------------------------------------- launch
extern "C" void kernel_launch(void* const* d_in, const int* in_sizes, int n_in,
                              void* d_out, int out_size, void* d_ws, size_t ws_size,
                              hipStream_t stream) {
    const int*   users     = (const int*)d_in[0];
    const int*   pos_items = (const int*)d_in[1];
    const int*   neg_items = (const int*)d_in[2];
    const float* user_emb  = (const float*)d_in[3];
    const float* item_emb1 = (const float*)d_in[4];
    const float* item_emb2 = (const float*)d_in[5];
    const float* feature   = (const float*)d_in[6];
    const float* w3        = (const float*)d_in[7];
    const float* W_gc      = (const float*)d_in[8];
    const float* b_gc      = (const float*)d_in[9];
    const float* W_bi      = (const float*)d_in[10];
    const float* b_bi      = (const float*)d_in[11];
    const int*   adj_rows  = (const int*)d_in[12];
    const int*   adj_cols  = (const int*)d_in[13];
    const float* adj_vals  = (const float*)d_in[14];
    const int nnz = in_sizes[14];

    const size_t nd = (size_t)NTOT * D;
    const int NB2 = (NSCAN + SCAN_CHUNK - 1) / SCAN_CHUNK;   // 392

    char* p = (char*)d_ws;
    float* n1    = (float*)p;                 p += NTOT * 4;
    float* n2    = (float*)p;                 p += NTOT * 4;
    unsigned short* ego0h  = (unsigned short*)p; p += nd * 2;
    unsigned short* ego1h  = (unsigned short*)p; p += nd * 2;
    unsigned short* ego2h  = (unsigned short*)p; p += nd * 2;
    unsigned short* side_h = (unsigned short*)p; p += nd * 2;
    unsigned short* Wp     = (unsigned short*)p; p += 8192 * 8 * 2;
    int*  row_off = (int*)p;                  p += (NTOT + 128) * 4;
    int*  cnt2    = (int*)p;                  p += (size_t)NSCAN * 4;
    int*  scanout = (int*)p;                  p += (size_t)NSCAN * 4;
    int*  bsum    = (int*)p;                  p += 512 * 4;
    int*  boff    = (int*)p;                  p += 512 * 4;
    int2* tmp8    = (int2*)p;                 p += (size_t)nnz * 8;
    unsigned* edges4 = (unsigned*)p;          p += (size_t)nnz * 4;

    float* out = (float*)d_out;

    {
        int ablocks = (NTOT * (D / 4) + 255) / 256;
        assemble_and_pack<<<32 + ablocks, 256, 0, stream>>>(
            user_emb, item_emb1, item_emb2, feature, W_gc, W_bi, ego0h, Wp);
    }

    // ---- CSR build: hist -> scan -> partition -> in-bucket row sort
    int chunk_sz = (nnz + NCHK - 1) / NCHK;
    hist_buckets<<<NCHK, 512, 0, stream>>>(adj_rows, cnt2, nnz, chunk_sz);
    scan_block_sums<<<NB2, SCAN_CHUNK, 0, stream>>>(cnt2, bsum, NSCAN);
    scan_small<<<1, 64, 0, stream>>>(bsum, boff, NB2);
    scan_chunks<<<NB2, SCAN_CHUNK, 0, stream>>>(cnt2, boff, scanout, NSCAN);
    partition_edges<<<NCHK, 512, 0, stream>>>(adj_rows, adj_cols, adj_vals, w3,
                                              scanout, tmp8, nnz, chunk_sz);
    bucket_sort<<<NBUK, 256, 0, stream>>>(tmp8, scanout, edges4, row_off, nnz);

    for (int k = 0; k < 2; ++k) {
        const unsigned short* Xh = (k == 0) ? ego0h : ego1h;
        unsigned short* egoNh    = (k == 0) ? ego1h : ego2h;
        float* nrm               = (k == 0) ? n1 : n2;

        spmm_csr_h<<<(NTOT + 3) / 4, 256, 0, stream>>>(row_off, edges4, Xh, side_h);
        layer_gemm_mfma<<<(NTOT + 63) / 64, 256, 0, stream>>>(
            side_h, Xh, Wp, k,
            b_gc + (size_t)k * D, b_bi + (size_t)k * D,
            egoNh, nrm);
    }

    {
        int total = 3 * BATCH_ * 384;
        gather_out<<<(total + 255) / 256, 256, 0, stream>>>(
            users, pos_items, neg_items,
            user_emb, item_emb1, item_emb2, feature,
            ego1h, ego2h, n1, n2, out);
    }
}

// Round 12
// 365.112 us; speedup vs baseline: 1.0967x; 1.0967x over previous
//
#include <hip/hip_runtime.h>
#include <math.h>

#define N_USER 50000
#define N_ITEM 50000
#define NTOT   100000
#define D      128
#define BATCH_ 4096
#define NEG_SLOPE 0.2f
#define EPS_ 1e-12f
#define SCAN_CHUNK 1024
#define NBUK 782            // buckets of 128 rows
#define NCHK 256            // edge chunks for partition
#define NSCAN (NBUK * NCHK) // 200192
#define BUKCAP 6144         // max edges/bucket for LDS sort (mean 4096, max ~4350)

typedef __attribute__((ext_vector_type(8))) short bfrag;
typedef __attribute__((ext_vector_type(4))) float f32x4;

static __device__ __forceinline__ float bf2f(unsigned short h) {
    return __uint_as_float(((unsigned)h) << 16);
}
static __device__ __forceinline__ unsigned short f2bf(float f) {
    unsigned u = __float_as_uint(f);
    u += 0x7fffu + ((u >> 16) & 1u);   // round-to-nearest-even
    return (unsigned short)(u >> 16);
}

// ---------------------------------------------------------------- ego0 assembly + W pack (merged)
__global__ void assemble_and_pack(const float* __restrict__ user_emb,
                                  const float* __restrict__ item_emb1,
                                  const float* __restrict__ item_emb2,
                                  const float* __restrict__ feature,
                                  const float* __restrict__ W_gc,
                                  const float* __restrict__ W_bi,
                                  unsigned short* __restrict__ ego0h,
                                  unsigned short* __restrict__ Wp) {
    if (blockIdx.x < 32) {
        // ---- W pre-pack (bf16, frag-major): 8192 threads
        int t = blockIdx.x * 256 + threadIdx.x;
        int lane  = t & 63;
        int nt    = (t >> 6) & 7;
        int kt    = (t >> 9) & 3;
        int mat   = (t >> 11) & 1;
        int layer = (t >> 12) & 1;
        const float* W = (mat ? W_bi : W_gc) + (size_t)layer * D * D;
        int n = nt * 16 + (lane & 15);
        int kbase = kt * 32 + (lane >> 4) * 8;
        unsigned short o8[8];
        #pragma unroll
        for (int e = 0; e < 8; ++e) o8[e] = f2bf(W[(size_t)(kbase + e) * D + n]);
        *(int4*)(Wp + (size_t)t * 8) = *(int4*)o8;
        return;
    }
    int t = (blockIdx.x - 32) * 256 + threadIdx.x;   // float4 slot
    const int total = NTOT * (D / 4);
    if (t >= total) return;
    int row = t >> 5;
    int q   = t & 31;
    int d0  = q * 4;
    const float* src;
    if (d0 < 64) {
        src = (row < N_USER) ? user_emb  + (size_t)row * 64 + d0
                             : item_emb1 + (size_t)(row - N_USER) * 64 + d0;
    } else {
        src = (row < N_USER) ? feature   + (size_t)row * 64 + (d0 - 64)
                             : item_emb2 + (size_t)(row - N_USER) * 64 + (d0 - 64);
    }
    float4 v = *(const float4*)src;
    ushort4 h;
    h.x = f2bf(v.x); h.y = f2bf(v.y); h.z = f2bf(v.z); h.w = f2bf(v.w);
    *(ushort4*)(ego0h + (size_t)row * D + d0) = h;
}

// ---------------------------------------------------------------- bucket histogram (chunk-blocks, 1024 thr)
__global__ __launch_bounds__(1024) void hist_buckets(const int* __restrict__ rows,
                                                     int* __restrict__ cnt2,
                                                     int nnz, int chunk_sz) {
    __shared__ int h[NBUK];
    for (int i = threadIdx.x; i < NBUK; i += 1024) h[i] = 0;
    __syncthreads();
    int c = blockIdx.x;
    int base = c * chunk_sz, end = min(base + chunk_sz, nnz);
    for (int e = base + threadIdx.x; e < end; e += 1024)
        atomicAdd(&h[rows[e] >> 7], 1);
    __syncthreads();
    for (int b = threadIdx.x; b < NBUK; b += 1024)
        cnt2[b * NCHK + c] = h[b];      // bucket-major: scan gives bucket-contiguous ranges
}

// ---------------------------------------------------------------- scan (3-pass, n = NSCAN)
__global__ __launch_bounds__(1024) void scan_block_sums(const int* __restrict__ cnt,
                                                        int* __restrict__ bsum, int n) {
    __shared__ int ws[16];
    int i = blockIdx.x * SCAN_CHUNK + threadIdx.x;
    int x = (i < n) ? cnt[i] : 0;
    #pragma unroll
    for (int d = 32; d >= 1; d >>= 1) x += __shfl_xor(x, d);
    int wid = threadIdx.x >> 6, lane = threadIdx.x & 63;
    if (lane == 0) ws[wid] = x;
    __syncthreads();
    if (threadIdx.x == 0) {
        int s = 0;
        #pragma unroll
        for (int k = 0; k < 16; ++k) s += ws[k];
        bsum[blockIdx.x] = s;
    }
}

__global__ void scan_small(const int* __restrict__ bsum, int* __restrict__ boff, int nb) {
    if (threadIdx.x == 0 && blockIdx.x == 0) {
        int acc = 0;
        for (int i = 0; i < nb; ++i) { boff[i] = acc; acc += bsum[i]; }
    }
}

__global__ __launch_bounds__(1024) void scan_chunks(const int* __restrict__ cnt,
                                                    const int* __restrict__ boff,
                                                    int* __restrict__ off, int n) {
    __shared__ int ws[16];
    int tid = threadIdx.x;
    int i = blockIdx.x * SCAN_CHUNK + tid;
    int x = (i < n) ? cnt[i] : 0;
    int v = x;
    #pragma unroll
    for (int d = 1; d < 64; d <<= 1) { int u = __shfl_up(v, d); if ((tid & 63) >= d) v += u; }
    int wid = tid >> 6, lane = tid & 63;
    if (lane == 63) ws[wid] = v;
    __syncthreads();
    if (wid == 0) {
        int s = (lane < 16) ? ws[lane] : 0;
        #pragma unroll
        for (int d = 1; d < 16; d <<= 1) { int u = __shfl_up(s, d); if (lane >= d) s += u; }
        if (lane < 16) ws[lane] = s;
    }
    __syncthreads();
    int woff = (wid == 0) ? 0 : ws[wid - 1];
    if (i < n) off[i] = boff[blockIdx.x] + woff + v - x;
}

// ---------------------------------------------------------------- partition into buckets (no global atomics, 1024 thr)
__global__ __launch_bounds__(1024) void partition_edges(
        const int* __restrict__ rows, const int* __restrict__ cols,
        const float* __restrict__ vals, const float* __restrict__ w3,
        const int* __restrict__ scanout, int2* __restrict__ tmp8,
        int nnz, int chunk_sz) {
    __shared__ int cur[NBUK];
    int c = blockIdx.x;
    for (int b = threadIdx.x; b < NBUK; b += 1024) cur[b] = scanout[b * NCHK + c];
    __syncthreads();
    const float w0 = w3[0], w1 = w3[1], w2 = w3[2];
    int base = c * chunk_sz, end = min(base + chunk_sz, nnz);
    for (int e = base + threadIdx.x; e < end; e += 1024) {
        int r = rows[e];
        float v = vals[e];
        float v2 = v * v;
        float comb = w0 * v + w1 * v2 + w2 * v2 * v2 * v2;
        int pos = atomicAdd(&cur[r >> 7], 1);
        tmp8[pos] = make_int2(((r & 127) << 17) | cols[e], __float_as_int(comb));
    }
}

// ---------------------------------------------------------------- in-bucket LDS counting sort -> 4B edges + row_off
__global__ __launch_bounds__(256) void bucket_sort(
        const int2* __restrict__ tmp8, const int* __restrict__ scanout,
        unsigned* __restrict__ edges4, int* __restrict__ row_off, int nnz) {
    __shared__ int hist[128], exc[129], cur[128];
    __shared__ unsigned st[BUKCAP];
    int b = blockIdx.x;
    int lo = scanout[b * NCHK];
    int hi = (b + 1 < NBUK) ? scanout[(b + 1) * NCHK] : nnz;
    int cnt = hi - lo;
    if (threadIdx.x < 128) hist[threadIdx.x] = 0;
    __syncthreads();
    for (int i = lo + threadIdx.x; i < hi; i += 256)
        atomicAdd(&hist[tmp8[i].x >> 17], 1);
    __syncthreads();
    if (threadIdx.x == 0) {
        int a = 0;
        for (int r = 0; r < 128; ++r) { exc[r] = a; a += hist[r]; }
        exc[128] = a;
    }
    __syncthreads();
    if (threadIdx.x < 128) {
        cur[threadIdx.x] = exc[threadIdx.x];
        int grow = b * 128 + threadIdx.x;
        if (grow <= NTOT) row_off[grow] = lo + exc[threadIdx.x];
    }
    __syncthreads();
    if (cnt <= BUKCAP) {
        for (int i = lo + threadIdx.x; i < hi; i += 256) {
            int2 t = tmp8[i];
            int rl = t.x >> 17;
            int p = atomicAdd(&cur[rl], 1);
            unsigned cb = (unsigned)f2bf(__int_as_float(t.y)) & 0x7FFFu;  // comb>0 -> sign 0
            st[p] = (cb << 17) | ((unsigned)t.x & 0x1FFFFu);
        }
        __syncthreads();
        for (int i = threadIdx.x; i < cnt; i += 256)
            edges4[lo + i] = st[i];                   // fully coalesced
    } else {
        // statistically unreachable fallback (cnt > BUKCAP)
        for (int i = lo + threadIdx.x; i < hi; i += 256) {
            int2 t = tmp8[i];
            int rl = t.x >> 17;
            int p = atomicAdd(&cur[rl], 1);
            unsigned cb = (unsigned)f2bf(__int_as_float(t.y)) & 0x7FFFu;
            edges4[lo + p] = (cb << 17) | ((unsigned)t.x & 0x1FFFFu);
        }
    }
}

// ---------------------------------------------------------------- SpMM (CSR, wave/row, 4-edge groups, 4-deep unroll)
__global__ __launch_bounds__(256) void spmm_csr_h(const int* __restrict__ row_off,
                                                  const unsigned* __restrict__ edges4,
                                                  const unsigned short* __restrict__ Xh,
                                                  unsigned short* __restrict__ side_h) {
    int row = (blockIdx.x * blockDim.x + threadIdx.x) >> 6;
    if (row >= NTOT) return;
    int lane = threadIdx.x & 63;
    int g = lane >> 4;        // edge slot 0..3
    int q = lane & 15;        // dim slice: dims q*8 .. q*8+7
    int s = row_off[row], e = row_off[row + 1];

    float a[8];
    #pragma unroll
    for (int j = 0; j < 8; ++j) a[j] = 0.f;

    for (int i = s; i < e; i += 16) {
        int i0 = i + g, i1 = i + 4 + g, i2 = i + 8 + g, i3 = i + 12 + g;
        unsigned e0 = (i0 < e) ? edges4[i0] : 0u;
        unsigned e1 = (i1 < e) ? edges4[i1] : 0u;
        unsigned e2 = (i2 < e) ? edges4[i2] : 0u;
        unsigned e3 = (i3 < e) ? edges4[i3] : 0u;
        float v0 = bf2f((unsigned short)(e0 >> 17));
        float v1 = bf2f((unsigned short)(e1 >> 17));
        float v2 = bf2f((unsigned short)(e2 >> 17));
        float v3 = bf2f((unsigned short)(e3 >> 17));
        int4 x0 = *(const int4*)(Xh + (size_t)(e0 & 0x1FFFFu) * D + q * 8);
        int4 x1 = *(const int4*)(Xh + (size_t)(e1 & 0x1FFFFu) * D + q * 8);
        int4 x2 = *(const int4*)(Xh + (size_t)(e2 & 0x1FFFFu) * D + q * 8);
        int4 x3 = *(const int4*)(Xh + (size_t)(e3 & 0x1FFFFu) * D + q * 8);
        const unsigned short* p0 = (const unsigned short*)&x0;
        const unsigned short* p1 = (const unsigned short*)&x1;
        const unsigned short* p2 = (const unsigned short*)&x2;
        const unsigned short* p3 = (const unsigned short*)&x3;
        #pragma unroll
        for (int j = 0; j < 8; ++j)
            a[j] += v0 * bf2f(p0[j]) + v1 * bf2f(p1[j])
                  + v2 * bf2f(p2[j]) + v3 * bf2f(p3[j]);
    }
    #pragma unroll
    for (int j = 0; j < 8; ++j) {
        a[j] += __shfl_xor(a[j], 16);
        a[j] += __shfl_xor(a[j], 32);
    }
    if (g == 0) {
        unsigned short o[8];
        #pragma unroll
        for (int j = 0; j < 8; ++j) o[j] = f2bf(a[j]);
        *(int4*)(side_h + (size_t)row * D + q * 8) = *(int4*)o;
    }
}

// ---------------------------------------------------------------- fused MFMA layer GEMM
__global__ __launch_bounds__(256) void layer_gemm_mfma(
        const unsigned short* __restrict__ side_h,
        const unsigned short* __restrict__ ego_h,
        const unsigned short* __restrict__ Wp, int layer,
        const float* __restrict__ bgc, const float* __restrict__ bbi,
        unsigned short* __restrict__ ego_out_h, float* __restrict__ norms) {
    __shared__ unsigned short Sl[64 * D];
    __shared__ unsigned short Pl[64 * D];
    __shared__ float sqp[4][64];

    const int r0  = blockIdx.x * 64;
    const int tid = threadIdx.x;
    const int lane = tid & 63;
    const int wv   = tid >> 6;

    #pragma unroll
    for (int it = 0; it < 4; ++it) {
        int c = tid + it * 256;
        int r = c >> 4;
        int q = c & 15;
        int row = r0 + r;
        int4 sv = make_int4(0, 0, 0, 0), ev = make_int4(0, 0, 0, 0);
        if (row < NTOT) {
            sv = *(const int4*)(side_h + (size_t)row * D + q * 8);
            ev = *(const int4*)(ego_h  + (size_t)row * D + q * 8);
        }
        int dst = (r * 256 + q * 16) ^ ((r & 7) << 4);
        *(int4*)((char*)Sl + dst) = sv;
        const unsigned short* sp = (const unsigned short*)&sv;
        const unsigned short* ep = (const unsigned short*)&ev;
        unsigned short pv[8];
        #pragma unroll
        for (int j = 0; j < 8; ++j) pv[j] = f2bf(bf2f(sp[j]) * bf2f(ep[j]));
        *(int4*)((char*)Pl + dst) = *(int4*)pv;
    }

    bfrag wg[4][2], wb[4][2];
    #pragma unroll
    for (int kt = 0; kt < 4; ++kt)
        #pragma unroll
        for (int n2 = 0; n2 < 2; ++n2) {
            int nt = wv * 2 + n2;
            size_t og = ((((size_t)(layer * 2 + 0) * 4 + kt) * 8 + nt) * 64 + lane) * 8;
            size_t ob = ((((size_t)(layer * 2 + 1) * 4 + kt) * 8 + nt) * 64 + lane) * 8;
            wg[kt][n2] = *(const bfrag*)(Wp + og);
            wb[kt][n2] = *(const bfrag*)(Wp + ob);
        }

    __syncthreads();

    f32x4 acc[4][2];
    #pragma unroll
    for (int m = 0; m < 4; ++m)
        #pragma unroll
        for (int n = 0; n < 2; ++n) acc[m][n] = (f32x4){0.f, 0.f, 0.f, 0.f};

    #pragma unroll
    for (int kt = 0; kt < 4; ++kt) {
        bfrag sf[4], pf[4];
        #pragma unroll
        for (int m = 0; m < 4; ++m) {
            int rowl = m * 16 + (lane & 15);
            int byte = (rowl * 256 + kt * 64 + (lane >> 4) * 16) ^ ((rowl & 7) << 4);
            sf[m] = *(const bfrag*)((const char*)Sl + byte);
            pf[m] = *(const bfrag*)((const char*)Pl + byte);
        }
        #pragma unroll
        for (int m = 0; m < 4; ++m)
            #pragma unroll
            for (int n = 0; n < 2; ++n) {
                acc[m][n] = __builtin_amdgcn_mfma_f32_16x16x32_bf16(sf[m], wg[kt][n], acc[m][n], 0, 0, 0);
                acc[m][n] = __builtin_amdgcn_mfma_f32_16x16x32_bf16(pf[m], wb[kt][n], acc[m][n], 0, 0, 0);
            }
    }

    float bsum[2];
    #pragma unroll
    for (int n = 0; n < 2; ++n) {
        int col = wv * 32 + n * 16 + (lane & 15);
        bsum[n] = bgc[col] + bbi[col];
    }

    float sq[4][4];
    #pragma unroll
    for (int m = 0; m < 4; ++m)
        #pragma unroll
        for (int r = 0; r < 4; ++r) sq[m][r] = 0.f;

    #pragma unroll
    for (int m = 0; m < 4; ++m) {
        int rowl = m * 16 + (lane >> 4) * 4;
        #pragma unroll
        for (int n = 0; n < 2; ++n) {
            int col = wv * 32 + n * 16 + (lane & 15);
            #pragma unroll
            for (int r = 0; r < 4; ++r) {
                float o = acc[m][n][r] + bsum[n];
                o = (o > 0.f) ? o : NEG_SLOPE * o;
                sq[m][r] += o * o;
                int row = r0 + rowl + r;
                if (row < NTOT)
                    ego_out_h[(size_t)row * D + col] = f2bf(o);
            }
        }
    }

    #pragma unroll
    for (int m = 0; m < 4; ++m)
        #pragma unroll
        for (int r = 0; r < 4; ++r) {
            float v = sq[m][r];
            #pragma unroll
            for (int off = 8; off >= 1; off >>= 1) v += __shfl_xor(v, off);
            if ((lane & 15) == 0) sqp[wv][m * 16 + (lane >> 4) * 4 + r] = v;
        }
    __syncthreads();
    if (tid < 64) {
        int row = r0 + tid;
        if (row < NTOT) {
            float s = sqp[0][tid] + sqp[1][tid] + sqp[2][tid] + sqp[3][tid];
            norms[row] = fmaxf(sqrtf(s), EPS_);
        }
    }
}

// ---------------------------------------------------------------- final gather (layer0 from raw f32 inputs)
__global__ void gather_out(const int* __restrict__ users,
                           const int* __restrict__ pos,
                           const int* __restrict__ neg,
                           const float* __restrict__ user_emb,
                           const float* __restrict__ item_emb1,
                           const float* __restrict__ item_emb2,
                           const float* __restrict__ feature,
                           const unsigned short* __restrict__ ego1h,
                           const unsigned short* __restrict__ ego2h,
                           const float* __restrict__ n1,
                           const float* __restrict__ n2,
                           float* __restrict__ out) {
    int t = blockIdx.x * blockDim.x + threadIdx.x;
    const int total = 3 * BATCH_ * 384;
    if (t >= total) return;
    int c = t % 384;
    int i = (t / 384) % BATCH_;
    int s = t / (384 * BATCH_);
    int idx  = (s == 0) ? users[i] : (s == 1 ? pos[i] : neg[i]);
    int node = (s == 0) ? idx : idx + N_USER;
    float val;
    if (c < 128) {
        if (s == 0)
            val = (c < 64) ? user_emb[(size_t)idx * 64 + c]
                           : feature[(size_t)idx * 64 + (c - 64)];
        else
            val = (c < 64) ? item_emb1[(size_t)idx * 64 + c]
                           : item_emb2[(size_t)idx * 64 + (c - 64)];
    } else if (c < 256) {
        val = bf2f(ego1h[(size_t)node * D + (c - 128)]) / n1[node];
    } else {
        val = bf2f(ego2h[(size_t)node * D + (c - 256)]) / n2[node];
    }
    out[t] = val;
}

// ---------------------------------------------------------------- launch
extern "C" void kernel_launch(void* const* d_in, const int* in_sizes, int n_in,
                              void* d_out, int out_size, void* d_ws, size_t ws_size,
                              hipStream_t stream) {
    const int*   users     = (const int*)d_in[0];
    const int*   pos_items = (const int*)d_in[1];
    const int*   neg_items = (const int*)d_in[2];
    const float* user_emb  = (const float*)d_in[3];
    const float* item_emb1 = (const float*)d_in[4];
    const float* item_emb2 = (const float*)d_in[5];
    const float* feature   = (const float*)d_in[6];
    const float* w3        = (const float*)d_in[7];
    const float* W_gc      = (const float*)d_in[8];
    const float* b_gc      = (const float*)d_in[9];
    const float* W_bi      = (const float*)d_in[10];
    const float* b_bi      = (const float*)d_in[11];
    const int*   adj_rows  = (const int*)d_in[12];
    const int*   adj_cols  = (const int*)d_in[13];
    const float* adj_vals  = (const float*)d_in[14];
    const int nnz = in_sizes[14];

    const size_t nd = (size_t)NTOT * D;
    const int NB2 = (NSCAN + SCAN_CHUNK - 1) / SCAN_CHUNK;   // 196

    char* p = (char*)d_ws;
    float* n1    = (float*)p;                 p += NTOT * 4;
    float* n2    = (float*)p;                 p += NTOT * 4;
    unsigned short* ego0h  = (unsigned short*)p; p += nd * 2;
    unsigned short* ego1h  = (unsigned short*)p; p += nd * 2;
    unsigned short* ego2h  = (unsigned short*)p; p += nd * 2;
    unsigned short* side_h = (unsigned short*)p; p += nd * 2;
    unsigned short* Wp     = (unsigned short*)p; p += 8192 * 8 * 2;
    int*  row_off = (int*)p;                  p += (NTOT + 128) * 4;
    int*  cnt2    = (int*)p;                  p += (size_t)NSCAN * 4;
    int*  scanout = (int*)p;                  p += (size_t)NSCAN * 4;
    int*  bsum    = (int*)p;                  p += 256 * 4;
    int*  boff    = (int*)p;                  p += 256 * 4;
    int2* tmp8    = (int2*)p;                 p += (size_t)nnz * 8;
    unsigned* edges4 = (unsigned*)p;          p += (size_t)nnz * 4;

    float* out = (float*)d_out;

    {
        int ablocks = (NTOT * (D / 4) + 255) / 256;
        assemble_and_pack<<<32 + ablocks, 256, 0, stream>>>(
            user_emb, item_emb1, item_emb2, feature, W_gc, W_bi, ego0h, Wp);
    }

    // ---- CSR build: hist -> scan -> partition -> in-bucket row sort
    int chunk_sz = (nnz + NCHK - 1) / NCHK;
    hist_buckets<<<NCHK, 1024, 0, stream>>>(adj_rows, cnt2, nnz, chunk_sz);
    scan_block_sums<<<NB2, SCAN_CHUNK, 0, stream>>>(cnt2, bsum, NSCAN);
    scan_small<<<1, 64, 0, stream>>>(bsum, boff, NB2);
    scan_chunks<<<NB2, SCAN_CHUNK, 0, stream>>>(cnt2, boff, scanout, NSCAN);
    partition_edges<<<NCHK, 1024, 0, stream>>>(adj_rows, adj_cols, adj_vals, w3,
                                               scanout, tmp8, nnz, chunk_sz);
    bucket_sort<<<NBUK, 256, 0, stream>>>(tmp8, scanout, edges4, row_off, nnz);

    for (int k = 0; k < 2; ++k) {
        const unsigned short* Xh = (k == 0) ? ego0h : ego1h;
        unsigned short* egoNh    = (k == 0) ? ego1h : ego2h;
        float* nrm               = (k == 0) ? n1 : n2;

        spmm_csr_h<<<(NTOT + 3) / 4, 256, 0, stream>>>(row_off, edges4, Xh, side_h);
        layer_gemm_mfma<<<(NTOT + 63) / 64, 256, 0, stream>>>(
            side_h, Xh, Wp, k,
            b_gc + (size_t)k * D, b_bi + (size_t)k * D,
            egoNh, nrm);
    }

    {
        int total = 3 * BATCH_ * 384;
        gather_out<<<(total + 255) / 256, 256, 0, stream>>>(
            users, pos_items, neg_items,
            user_emb, item_emb1, item_emb2, feature,
            ego1h, ego2h, n1, n2, out);
    }
}